// Round 1
// baseline (614.590 us; speedup 1.0000x reference)
//
#include <hip/hip_runtime.h>
#include <hip/hip_bf16.h>
#include <stdint.h>

typedef float  f32x4   __attribute__((ext_vector_type(4)));
typedef short  short8  __attribute__((ext_vector_type(8)));
typedef short  short4v __attribute__((ext_vector_type(4)));

#define TOTAL 8192

// async global->LDS, 16B per lane; LDS dest = uniform base + lane*16
__device__ __forceinline__ void dma16(const void* g, void* l) {
  __builtin_amdgcn_global_load_lds(
      (const __attribute__((address_space(1))) unsigned int*)g,
      (__attribute__((address_space(3))) unsigned int*)l,
      16, 0, 0);
}

// Wt[s][v][u] = bf16(w_s[u][v] * 1/sqrt(512))  -- transpose + scale-fold + cvt
__global__ __launch_bounds__(256) void prep_wt(
    const float* __restrict__ w0, const float* __restrict__ w1,
    const float* __restrict__ w2, const float* __restrict__ w3,
    __hip_bfloat16* __restrict__ wt) {
  __shared__ float T[64][65];
  const int s = blockIdx.z;
  const float* w = (s == 0) ? w0 : (s == 1) ? w1 : (s == 2) ? w2 : w3;
  const int u0 = blockIdx.y * 64, v0 = blockIdx.x * 64;
  const int tx = threadIdx.x & 63, ty = threadIdx.x >> 6;
#pragma unroll
  for (int k = 0; k < 16; ++k) {
    int r = ty * 16 + k;
    T[r][tx] = w[(size_t)(u0 + r) * 512 + v0 + tx];
  }
  __syncthreads();
  const float scale = 0.04419417382415922f;  // 1/sqrt(512)
#pragma unroll
  for (int k = 0; k < 16; ++k) {
    int r = ty * 16 + k;
    wt[((size_t)s << 18) + (size_t)(v0 + r) * 512 + u0 + tx] =
        __float2bfloat16(T[tx][r] * scale);
  }
}

// One segment GEMM: rows = (n,j) n-major (row = n*D + j), M_d = 8192*D,
// K = 512 (u), N = 512 (v).  BM=64, BN=512 (full v -> x read exactly once),
// BK=32. 256 threads = 4 waves; wave w covers cols [w*128, w*128+128).
template <int D, int SEGOFF>
__device__ __forceinline__ void seg_gemm(
    const float* __restrict__ x, const __hip_bfloat16* __restrict__ wt,
    float* __restrict__ out, int rt) {
  constexpr int BM = 64, BK = 32, LDA = BK + 8;  // 80B row stride: 2-way-free b64 frag reads
  constexpr int CHUNK = BK * D;                  // fp32 elems per n per K-iter
  extern __shared__ char smem[];
  __hip_bfloat16* As = (__hip_bfloat16*)smem;                    // 64*40*2 = 5120 B
  __hip_bfloat16* Bs = (__hip_bfloat16*)(smem + BM * LDA * 2);   // 512*32*2 = 32768 B

  const int tid  = threadIdx.x;
  const int lane = tid & 63;
  const int wv   = tid >> 6;
  const int row0 = rt * BM;
  const int nF   = row0 / D;
  const int nL   = (row0 + BM - 1) / D;
  const int F4   = ((nL - nF + 1) * CHUNK) >> 2;  // float4 count to sweep
  const int q  = lane >> 4, cl = lane & 15;

  f32x4 acc[4][8] = {};

  for (int k0 = 0; k0 < 512; k0 += BK) {
    __syncthreads();
    // ---- stage A: coalesced fp32 float4 loads, cvt, de-interleave j into rows ----
    for (int e = tid; e < F4; e += 256) {
      int p4 = e << 2;
      int nb = p4 / CHUNK;            // compile-time-const divisor (magic mul)
      int p  = p4 - nb * CHUNK;
      int n  = nF + nb;
      const float* gp = x + (size_t)n * TOTAL + SEGOFF + k0 * D + p;
      float4 vv = *(const float4*)gp;  // 16B-aligned: SEGOFF,k0*D,p all %4==0
      if (D == 1) {
        int r = n - row0;
        if ((unsigned)r < (unsigned)BM) {
          __hip_bfloat16 tmp[4];
          tmp[0] = __float2bfloat16(vv.x); tmp[1] = __float2bfloat16(vv.y);
          tmp[2] = __float2bfloat16(vv.z); tmp[3] = __float2bfloat16(vv.w);
          *(short4v*)&As[r * LDA + p] = *(const short4v*)tmp;
        }
      } else {
        const float* vf = (const float*)&vv;
#pragma unroll
        for (int c = 0; c < 4; ++c) {
          int pc = p + c;
          int u  = pc / D;             // const divisor
          int j  = pc - u * D;
          int r  = n * D + j - row0;
          if ((unsigned)r < (unsigned)BM)
            As[r * LDA + u] = __float2bfloat16(vf[c]);
        }
      }
    }
    // ---- stage B: DMA Wt[v][k0:k0+32) -> Bs[512][32], 1KB per instr ----
#pragma unroll
    for (int t = 0; t < 8; ++t) {
      int i    = wv * 8 + t;
      int vrow = i * 16 + (lane >> 2);
      const __hip_bfloat16* gs = wt + (size_t)vrow * 512 + k0 + ((lane & 3) << 3);
      dma16(gs, Bs + i * 512);
    }
    __syncthreads();
    // ---- compute: 4 A-frags + 8 B-frags -> 32 MFMA ----
    short8 afr[4];
#pragma unroll
    for (int mi = 0; mi < 4; ++mi) {
      const __hip_bfloat16* pa = As + (mi * 16 + cl) * LDA + q * 8;
      short4v lo = *(const short4v*)pa;
      short4v hi = *(const short4v*)(pa + 4);
      afr[mi] = __builtin_shufflevector(lo, hi, 0, 1, 2, 3, 4, 5, 6, 7);
    }
#pragma unroll
    for (int ni = 0; ni < 8; ++ni) {
      const __hip_bfloat16* pb = Bs + (size_t)(wv * 128 + ni * 16 + cl) * BK + q * 8;
      short8 bfr = *(const short8*)pb;
#pragma unroll
      for (int mi = 0; mi < 4; ++mi)
        acc[mi][ni] = __builtin_amdgcn_mfma_f32_16x16x32_bf16(afr[mi], bfr, acc[mi][ni], 0, 0, 0);
    }
  }
  // ---- epilogue: C/D layout col=lane&15, row=(lane>>4)*4+reg (m89-verified) ----
#pragma unroll
  for (int mi = 0; mi < 4; ++mi) {
#pragma unroll
    for (int ni = 0; ni < 8; ++ni) {
#pragma unroll
      for (int rg = 0; rg < 4; ++rg) {
        int R = row0 + mi * 16 + q * 4 + rg;
        int n = R / D;
        int j = R - n * D;
        int v = wv * 128 + ni * 16 + cl;
        out[(size_t)n * TOTAL + SEGOFF + v * D + j] = acc[mi][ni][rg];
      }
    }
  }
}

// Row-tile counts: d=1:128, d=3:384, d=5:640, d=7:896  => 2048 blocks total
__global__ __launch_bounds__(256, 2) void linear_main(
    const float* __restrict__ x, const __hip_bfloat16* __restrict__ wt,
    float* __restrict__ out) {
  int bx = blockIdx.x;
  if (bx < 128)        seg_gemm<1, 0>   (x, wt,             out, bx);
  else if (bx < 512)   seg_gemm<3, 512> (x, wt + (1 << 18), out, bx - 128);
  else if (bx < 1152)  seg_gemm<5, 2048>(x, wt + (2 << 18), out, bx - 512);
  else                 seg_gemm<7, 4608>(x, wt + (3 << 18), out, bx - 1152);
}

extern "C" void kernel_launch(void* const* d_in, const int* in_sizes, int n_in,
                              void* d_out, int out_size, void* d_ws, size_t ws_size,
                              hipStream_t stream) {
  const float* x  = (const float*)d_in[0];
  const float* w0 = (const float*)d_in[1];
  const float* w1 = (const float*)d_in[2];
  const float* w2 = (const float*)d_in[3];
  const float* w3 = (const float*)d_in[4];
  __hip_bfloat16* wt = (__hip_bfloat16*)d_ws;  // needs 2 MB scratch
  float* out = (float*)d_out;

  hipLaunchKernelGGL(prep_wt, dim3(8, 8, 4), dim3(256), 0, stream,
                     w0, w1, w2, w3, wt);
  hipLaunchKernelGGL(linear_main, dim3(2048), dim3(256), 37888, stream,
                     x, wt, out);
}